// Round 10
// baseline (626.475 us; speedup 1.0000x reference)
//
#include <hip/hip_runtime.h>
#include <stdint.h>

// Problem (fp32 in / fp32 out): out = relu((x + (x@Wv^T+bv)@Wo^T + bo) @ Wn^T + bn)
//   softmax over a single score == 1 -> q,k path is dead code.
// Reformulated: out = relu(x@Wn^T + v@Wm^T + biasTot)
//   v  = x@Wv^T + bv          [8192 x 64]
//   Wm = Wn @ Wo              [4096 x 64]
//   biasTot = bn + Wn @ bo    [4096]
// Round 14: k_main = DOUBLE-BUFFERED stage-ahead, __syncthreads-only sync.
//   R13 post-mortem: duration == MFMA-time + DS-time + stage-drain (pipes
//   fully serialize in the single-buffered lockstep loop; MfmaUtil pinned
//   ~48% across 3 geometries). Fix: per tile { issue stage(t+1)->buf s;
//   compute(t) from buf c; __syncthreads }. The syncthreads vmcnt(0) drain
//   becomes free (loads issued ~1300cy earlier, landed under compute).
//   Race-free by construction: barrier at end of t-1 guarantees buf c staged
//   (all threads drained) AND buf s free (all done reading) — R11's
//   stage-before-guarantee bug avoided. BK=32 -> dbuf LDS 48KB -> keeps
//   2 blocks/CU. Swizzle slot^=(row>>1)&3 (pre-swizzled global source) ->
//   pure 2-way bank access (free, m136).
//   256x128 tile, 4 waves 2Mx2N, wave 128x64, acc[8][4]. 130 K-tiles
//   (128 X/Wn @BK=32 + 2 V/Wm tail @K=32 each). Grid 1024, plain map.
// Aux unchanged (k_cvt fused grid-stride + kT; k_prep round-0).

typedef unsigned short u16;
typedef float f32x4 __attribute__((ext_vector_type(4)));
typedef __bf16 bf16x8 __attribute__((ext_vector_type(8)));
typedef u16 u16x8 __attribute__((ext_vector_type(8)));

__device__ __forceinline__ float b2f(u16 u) {
  union { unsigned int i; float f; } x; x.i = ((unsigned int)u) << 16; return x.f;
}
__device__ __forceinline__ u16 f2b(float f) {  // round-to-nearest-even
  union { float f; unsigned int i; } x; x.f = f;
  unsigned int r = x.i + 0x7FFFu + ((x.i >> 16) & 1u);
  return (u16)(r >> 16);
}

// async global->LDS, 16B per lane; lds base wave-uniform (lane lands at base + lane*16B)
__device__ __forceinline__ void gl_lds16(const u16* g, u16* l) {
#if __has_builtin(__builtin_amdgcn_global_load_lds)
  __builtin_amdgcn_global_load_lds((__attribute__((address_space(1))) void*)g,
                                   (__attribute__((address_space(3))) void*)l, 16, 0, 0);
#else
  int lane = threadIdx.x & 63;
  *(u16x8*)(l + lane * 8) = *(const u16x8*)g;
#endif
}

__device__ __forceinline__ f32x4 mfma16(bf16x8 a, bf16x8 b, f32x4 c) {
  return __builtin_amdgcn_mfma_f32_16x16x32_bf16(a, b, c, 0, 0, 0);
}

// ---------------------------------------------------------------------------
// k_cvt: blocks [0,64):   WoT[a][k] = bf16(Wo[k][a])  (kT body, round-0)
//        blocks [64,2112): grid-stride fp32->bf16 cvt for x, Wn, Wv
// ---------------------------------------------------------------------------
#define XCH 4194304L   // 33554432/8  (x 8-elem groups)
#define WNCH 2097152L  // 16777216/8  (Wn groups)
#define TOTG 6324224L  // + 32768 Wv groups
__global__ __launch_bounds__(256) void k_cvt(
    const float* __restrict__ x, const float* __restrict__ Wn,
    const float* __restrict__ Wv, const float* __restrict__ Wo,
    u16* __restrict__ xb, u16* __restrict__ Wnb, u16* __restrict__ Wvb,
    u16* __restrict__ WoT) {
  __shared__ __align__(16) u16 t[64 * 72];
  if (blockIdx.x < 64) {
    const int b = blockIdx.x;
    const int tid = threadIdx.x;
    {
      int k = tid >> 2, a0 = (tid & 3) * 16;
      const float* src = &Wo[(size_t)(b * 64 + k) * 64 + a0];
#pragma unroll
      for (int q = 0; q < 4; ++q) {
        f32x4 v = *(const f32x4*)&src[q * 4];
#pragma unroll
        for (int e = 0; e < 4; ++e) t[k * 72 + a0 + q * 4 + e] = f2b(v[e]);
      }
    }
    __syncthreads();
    {
      int a = tid >> 2, k0 = (tid & 3) * 16;
      u16x8 o0, o1;
#pragma unroll
      for (int j = 0; j < 8; ++j) o0[j] = t[(k0 + j) * 72 + a];
#pragma unroll
      for (int j = 0; j < 8; ++j) o1[j] = t[(k0 + 8 + j) * 72 + a];
      *(u16x8*)&WoT[(size_t)a * 4096 + b * 64 + k0] = o0;
      *(u16x8*)&WoT[(size_t)a * 4096 + b * 64 + k0 + 8] = o1;
    }
    return;
  }
  long i = (long)(blockIdx.x - 64) * 256 + threadIdx.x;
  const long stride = 2048L * 256;
  for (; i < TOTG; i += stride) {
    const float* src; u16* dst; long off;
    if (i < XCH) { src = x; dst = xb; off = i * 8; }
    else if (i < XCH + WNCH) { src = Wn; dst = Wnb; off = (i - XCH) * 8; }
    else { src = Wv; dst = Wvb; off = (i - XCH - WNCH) * 8; }
    f32x4 a = *(const f32x4*)&src[off];
    f32x4 b = *(const f32x4*)&src[off + 4];
    u16x8 o;
#pragma unroll
    for (int e = 0; e < 4; ++e) { o[e] = f2b(a[e]); o[4 + e] = f2b(b[e]); }
    *(u16x8*)&dst[off] = o;
  }
}

// ---------------------------------------------------------------------------
// gemm_n64 (identical to round 0)
// ---------------------------------------------------------------------------
#define PBK 128
__device__ void gemm_n64(const u16* __restrict__ A, const u16* __restrict__ B,
                         u16* __restrict__ C, const float* __restrict__ bias,
                         long m0, u16* lA, u16* lB) {
  const int tid = threadIdx.x;
  const int w = tid >> 6, l = tid & 63;
  f32x4 acc[4];
#pragma unroll
  for (int nt = 0; nt < 4; ++nt) acc[nt] = (f32x4)(0.f);

  for (int k0 = 0; k0 < 4096; k0 += PBK) {
    __syncthreads();
#pragma unroll
    for (int i = 0; i < 4; ++i) {
      int row = w * 16 + i * 4 + (l >> 4);
      int p = (l & 15) ^ (i * 4 + (l >> 4));
      gl_lds16(A + (m0 + row) * (long)4096 + k0 + p * 8, lA + (w * 16 + i * 4) * PBK);
      gl_lds16(B + (long)row * 4096 + k0 + p * 8, lB + (w * 16 + i * 4) * PBK);
    }
    __syncthreads();
#pragma unroll
    for (int kk = 0; kk < 4; ++kk) {
      int slotA = ((kk * 4 + (l >> 4)) ^ (l & 15)) * 8;
      bf16x8 af = *(const bf16x8*)&lA[(w * 16 + (l & 15)) * PBK + slotA];
#pragma unroll
      for (int nt = 0; nt < 4; ++nt) {
        bf16x8 bf = *(const bf16x8*)&lB[(nt * 16 + (l & 15)) * PBK + slotA];
        acc[nt] = mfma16(af, bf, acc[nt]);
      }
    }
  }
#pragma unroll
  for (int nt = 0; nt < 4; ++nt) {
    int col = nt * 16 + (l & 15);
    float bb = bias ? bias[col] : 0.f;
#pragma unroll
    for (int r = 0; r < 4; ++r) {
      long row = m0 + w * 16 + (l >> 4) * 4 + r;
      C[row * 64 + col] = f2b(acc[nt][r] + bb);
    }
  }
}

// ---------------------------------------------------------------------------
// k_prep (identical to round 0)
// ---------------------------------------------------------------------------
__global__ __launch_bounds__(256, 2) void k_prep(
    const u16* __restrict__ xb, const u16* __restrict__ Wvb, const float* __restrict__ bv,
    const u16* __restrict__ Wnb, const u16* __restrict__ WoT,
    const float* __restrict__ bo, const float* __restrict__ bn,
    u16* __restrict__ V, u16* __restrict__ Wm, float* __restrict__ biasTot) {
  __shared__ __align__(16) u16 lA[64 * PBK];
  __shared__ __align__(16) u16 lB[64 * PBK];
  const int bid = blockIdx.x;
  if (bid < 128) {
    gemm_n64(xb, Wvb, V, bv, (long)bid * 64, lA, lB);
  } else if (bid < 192) {
    gemm_n64(Wnb, WoT, Wm, nullptr, (long)(bid - 128) * 64, lA, lB);
  } else {
    const int w = threadIdx.x >> 6, l = threadIdx.x & 63;
    const int n = (bid - 192) * 4 + w;
    float s = 0.f;
#pragma unroll
    for (int j = 0; j < 8; ++j) {
      int off = (j * 64 + l) * 8;
      u16x8 a = *(const u16x8*)&Wnb[(size_t)n * 4096 + off];
      f32x4 c0 = *(const f32x4*)&bo[off];
      f32x4 c1 = *(const f32x4*)&bo[off + 4];
#pragma unroll
      for (int e = 0; e < 4; ++e) s += b2f(a[e]) * c0[e] + b2f(a[4 + e]) * c1[e];
    }
#pragma unroll
    for (int o = 32; o > 0; o >>= 1) s += __shfl_xor(s, o, 64);
    if (l == 0) biasTot[n] = s + bn[n];
  }
}

// ---------------------------------------------------------------------------
// k_main (ROUND-14): 256x128 tile, 256 thr / 4 waves (wm=w>>1, wn=w&1),
//   per-wave 128x64 out = acc[8][4]. BK=32, 130 K-tiles (128 X/Wn + 2 V/Wm).
// DOUBLE-BUFFERED: per tile t { issue 6 gl_lds16 for t+1 -> buf s;
//   compute t from buf c (12 ds_read_b128 + 32 MFMA); __syncthreads }.
//   Stage loads land under the compute shadow -> the syncthreads vmcnt(0)
//   drain is ~free; DS pipe (stage writes + frag reads) overlaps MFMA pipe.
// LDS 48KB: buf b at b*12288 elems. A 256x32 at [0,8192), B 128x32 at
//   [8192,12288). Row = 32 elems (64B, 4 x 16B slots).
//   Swizzle LDS[r][p] = global[r][p ^ ((r>>1)&3)]:
//     stage: thread t covers row (op*64 + t>>2), phys slot t&3, global slot
//            pre-swizzled (t&3)^((t>>3)&3)  [ (t>>3)&3 == (rowS>>1)&3 ]
//     read : frag row R=...+frow, global slot g=l>>4, phys slot
//            g^((frow>>1)&3)  -> pure 2-way bank aliasing (free).
// ---------------------------------------------------------------------------
__global__ __launch_bounds__(256, 2) void k_main(
    const u16* __restrict__ X, const u16* __restrict__ Wn,
    const u16* __restrict__ V, const u16* __restrict__ Wm,
    const float* __restrict__ biasTot, float* __restrict__ Out) {
  __shared__ __align__(16) u16 smem[24576];  // 48 KB (2 x 12288 elems)
  const int tid = threadIdx.x;
  const int w = tid >> 6, l = tid & 63;
  const int wm = w >> 1, wn = w & 1;
  const long mBase = (long)(blockIdx.x >> 5) * 256;
  const int  nBase = (int)(blockIdx.x & 31) * 128;

  // staging constants
  const int rowS = w * 16 + (l >> 2);            // row within 64-row op (0..63)
  const int gsl  = ((l & 3) ^ ((l >> 3) & 3)) * 8;  // pre-swizzled global slot (elems)
  const int ldsS = w * 512;                      // wave base within op (elems)

  // fragment-read constants
  const int frow = l & 15;
  const int slotE = ((l >> 4) ^ ((frow >> 1) & 3)) * 8;  // swizzled phys slot (elems)
  const int aOff = wm * 4096 + frow * 32 + slotE;        // + mt*512
  const int bOff = 8192 + wn * 2048 + frow * 32 + slotE; // + nt*512

  f32x4 acc[8][4];
#pragma unroll
  for (int mt = 0; mt < 8; ++mt)
#pragma unroll
    for (int nt = 0; nt < 4; ++nt) acc[mt][nt] = (f32x4)(0.f);

  // stage tile tt into buffer at elem offset sb (6 gl_lds16 per thread)
  auto stage = [&](int tt, int sb) {
    const u16 *pA, *pB; long lda, ko;
    if (tt < 128) { pA = X; pB = Wn; lda = 4096; ko = (long)tt * 32; }
    else         { pA = V; pB = Wm; lda = 64;   ko = (long)(tt - 128) * 32; }
#pragma unroll
    for (int op = 0; op < 4; ++op)   // A: 256 rows
      gl_lds16(pA + (mBase + op * 64 + rowS) * lda + ko + gsl,
               smem + sb + op * 2048 + ldsS);
#pragma unroll
    for (int op = 0; op < 2; ++op)   // B: 128 rows
      gl_lds16(pB + ((long)nBase + op * 64 + rowS) * lda + ko + gsl,
               smem + sb + 8192 + op * 2048 + ldsS);
  };

  // prologue: tile 0 -> buf 0
  stage(0, 0);
  __syncthreads();

  for (int t = 0; t < 130; ++t) {
    const int cb = (t & 1) * 12288;
    if (t < 129) stage(t + 1, ((t + 1) & 1) * 12288);  // issue BEFORE compute
    // compute tile t from buf cb
    bf16x8 af[8], bf[4];
#pragma unroll
    for (int mt = 0; mt < 8; ++mt)
      af[mt] = *(const bf16x8*)&smem[cb + aOff + mt * 512];
#pragma unroll
    for (int nt = 0; nt < 4; ++nt)
      bf[nt] = *(const bf16x8*)&smem[cb + bOff + nt * 512];
    __builtin_amdgcn_s_setprio(1);
#pragma unroll
    for (int mt = 0; mt < 8; ++mt)
#pragma unroll
      for (int nt = 0; nt < 4; ++nt)
        acc[mt][nt] = mfma16(af[mt], bf[nt], acc[mt][nt]);
    __builtin_amdgcn_s_setprio(0);
    // barrier: (a) drains this thread's stage loads (vmcnt0 - free, issued
    // ~1300cy ago); (b) all waves done reading cb -> next tile may overwrite.
    __syncthreads();
  }

  // epilogue: bias + relu, fp32; per-wave LDS transpose (4 KB/wave)
  float* eb = ((float*)smem) + w * 1024;
  float bt[4];
#pragma unroll
  for (int nt = 0; nt < 4; ++nt) bt[nt] = biasTot[nBase + wn * 64 + nt * 16 + frow];
  const int fsl = l >> 4;
#pragma unroll
  for (int mt = 0; mt < 8; ++mt) {
#pragma unroll
    for (int nt = 0; nt < 4; ++nt) {
#pragma unroll
      for (int r = 0; r < 4; ++r) {
        float val = acc[mt][nt][r] + bt[nt];
        eb[(fsl * 4 + r) * 64 + nt * 16 + frow] = fmaxf(val, 0.f);
      }
    }
    int rr = l >> 2, c0 = (l & 3) * 16;
    long grow = mBase + wm * 128 + mt * 16 + rr;
    int gcol = nBase + wn * 64 + c0;
    f32x4 o0 = *(const f32x4*)&eb[rr * 64 + c0];
    f32x4 o1 = *(const f32x4*)&eb[rr * 64 + c0 + 4];
    f32x4 o2 = *(const f32x4*)&eb[rr * 64 + c0 + 8];
    f32x4 o3 = *(const f32x4*)&eb[rr * 64 + c0 + 12];
    *(f32x4*)&Out[grow * 4096 + gcol] = o0;
    *(f32x4*)&Out[grow * 4096 + gcol + 4] = o1;
    *(f32x4*)&Out[grow * 4096 + gcol + 8] = o2;
    *(f32x4*)&Out[grow * 4096 + gcol + 12] = o3;
    __syncthreads();  // eb reused next mt by all waves of this block
  }
}

// ---------------------------------------------------------------------------
extern "C" void kernel_launch(void* const* d_in, const int* in_sizes, int n_in,
                              void* d_out, int out_size, void* d_ws, size_t ws_size,
                              hipStream_t stream) {
  const float* x  = (const float*)d_in[0];
  const float* Wv = (const float*)d_in[5];
  const float* bv = (const float*)d_in[6];
  const float* Wo = (const float*)d_in[7];
  const float* bo = (const float*)d_in[8];
  const float* Wn = (const float*)d_in[9];
  const float* bn = (const float*)d_in[10];
  float* out = (float*)d_out;

  char* ws = (char*)d_ws;
  u16* xb  = (u16*)ws;                             // 8192*4096*2 = 64 MB
  u16* Wnb = (u16*)(ws + (64L << 20));             // 4096*4096*2 = 32 MB
  u16* Wvb = (u16*)(ws + (96L << 20));             // 64*4096*2   = 512 KB
  u16* WoT = (u16*)(ws + (96L << 20) + (512 << 10));   // 512 KB
  u16* V   = (u16*)(ws + (97L << 20));             // 8192*64*2   = 1 MB
  u16* Wm  = (u16*)(ws + (98L << 20));             // 4096*64*2   = 512 KB
  float* biasTot = (float*)(ws + (98L << 20) + (512 << 10));  // 16 KB

  k_cvt<<<dim3(2112), dim3(256), 0, stream>>>(x, Wn, Wv, Wo, xb, Wnb, Wvb, WoT);
  k_prep<<<dim3(1216), dim3(256), 0, stream>>>(xb, Wvb, bv, Wnb, WoT, bo, bn, V, Wm, biasTot);
  k_main<<<dim3(1024), dim3(256), 0, stream>>>(xb, Wnb, V, Wm, biasTot, out);
}